// Round 4
// baseline (13429.565 us; speedup 1.0000x reference)
//
#include <hip/hip_runtime.h>
#include <hip/hip_fp16.h>

#define T_LEN 2048
#define HID   2048
#define G4    8192
#define NV    128

typedef _Float16 h2_t __attribute__((ext_vector_type(2)));
typedef unsigned u32x4 __attribute__((ext_vector_type(4)));

__device__ __forceinline__ float uplo(unsigned u) {
  return __half2float(__ushort_as_half((unsigned short)(u & 0xffffu)));
}
__device__ __forceinline__ float uphi(unsigned u) {
  return __half2float(__ushort_as_half((unsigned short)(u >> 16)));
}
__device__ __forceinline__ unsigned pku(float a, float b) {
  unsigned lo = (unsigned)__half_as_ushort(__float2half_rn(a));
  unsigned hi = (unsigned)__half_as_ushort(__float2half_rn(b));
  return lo | (hi << 16);
}
__device__ __forceinline__ h2_t pk2(float a, float bb) {
  return __builtin_bit_cast(h2_t, __builtin_amdgcn_cvt_pkrtz(a, bb));
}

// Coherent (cache-bypassing) 16B load.
__device__ __forceinline__ uint4 ld_sc16(const unsigned* p) {
  uint4 r;
  asm volatile("global_load_dwordx4 %0, %1, off sc0 sc1\n\ts_waitcnt vmcnt(0)"
               : "=v"(r) : "v"(p) : "memory");
  return r;
}
// Coherent 16B store, drained (ack'd at coherence point before return).
// Payload must be an ext_vector type: clang can't map struct uint4 to a
// "v" INPUT constraint ("indirect register inputs" error on gfx950).
__device__ __forceinline__ void st_sc16(unsigned* p, u32x4 v) {
  asm volatile("global_store_dwordx4 %0, %1, off sc0 sc1\n\ts_waitcnt vmcnt(0)"
               :: "v"(p), "v"(v) : "memory");
}
// Coherent 4B store (fire-and-forget).
__device__ __forceinline__ void st_sc4(unsigned* p, unsigned v) {
  asm volatile("global_store_dword %0, %1, off sc0 sc1"
               :: "v"(p), "v"(v) : "memory");
}

__device__ __forceinline__ float fsigmoid(float x) {
  return __builtin_amdgcn_rcpf(1.f + __expf(-x));
}
__device__ __forceinline__ float ftanh(float x) {
  return 2.f * __builtin_amdgcn_rcpf(1.f + __expf(-2.f * x)) - 1.f;
}

// Wave-wide poll: 64 lanes x dwordx4 = 256 flags checked per probe.
// Flag value for row rho is rho+1 (flags zeroed each launch by zero_flags).
__device__ __forceinline__ void poll_flags(const unsigned* f, unsigned want,
                                           int lane) {
  const unsigned* p = f + 4 * lane;
  int sp = 0;
  for (;;) {
    uint4 u = ld_sc16(p);
    bool ok = (u.x == want) & (u.y == want) & (u.z == want) & (u.w == want);
    if (__all(ok)) break;
    if (++sp > 8) __builtin_amdgcn_s_sleep(1);
    if (sp > (1 << 15)) break;   // safety valve
  }
}

// Zero the flag arrays with coherent stores (visible to the L2-bypassing poll
// loads). Graph-capture-legal replacement for hipMemsetAsync.
__global__ __launch_bounds__(256) void zero_flags(unsigned* f, int n4) {
  u32x4 z = {0u, 0u, 0u, 0u};
  for (int i = blockIdx.x * 256 + threadIdx.x; i < n4; i += gridDim.x * 256)
    st_sc16(f + 4 * (size_t)i, z);
}

// ---------------- GEMM: C[M][N] = A[M][K] @ B[N][K]^T + (b1+b2)[N] ----------------
__global__ __launch_bounds__(256, 2) void gemm_bias(
    const float* __restrict__ A, const float* __restrict__ B,
    const float* __restrict__ b1, const float* __restrict__ b2,
    float* __restrict__ C)
{
  const int N = 8192, K = 2048;
  __shared__ float As[32][68];
  __shared__ float Bs[32][68];
  const int tid = threadIdx.x;
  const int tx = tid & 15, ty = tid >> 4;
  const int row0 = blockIdx.y * 64, col0 = blockIdx.x * 64;
  const int lk = (tid & 7) * 4, lr = tid >> 3;
  float acc[4][4] = {};
  for (int k0 = 0; k0 < K; k0 += 32) {
    float4 a0 = *(const float4*)&A[(size_t)(row0 + lr)      * K + k0 + lk];
    float4 a1 = *(const float4*)&A[(size_t)(row0 + lr + 32) * K + k0 + lk];
    float4 bb0 = *(const float4*)&B[(size_t)(col0 + lr)      * K + k0 + lk];
    float4 bb1 = *(const float4*)&B[(size_t)(col0 + lr + 32) * K + k0 + lk];
    __syncthreads();
    As[lk+0][lr] = a0.x;  As[lk+1][lr] = a0.y;  As[lk+2][lr] = a0.z;  As[lk+3][lr] = a0.w;
    As[lk+0][lr+32] = a1.x; As[lk+1][lr+32] = a1.y; As[lk+2][lr+32] = a1.z; As[lk+3][lr+32] = a1.w;
    Bs[lk+0][lr] = bb0.x; Bs[lk+1][lr] = bb0.y; Bs[lk+2][lr] = bb0.z; Bs[lk+3][lr] = bb0.w;
    Bs[lk+0][lr+32] = bb1.x; Bs[lk+1][lr+32] = bb1.y; Bs[lk+2][lr+32] = bb1.z; Bs[lk+3][lr+32] = bb1.w;
    __syncthreads();
    #pragma unroll
    for (int kk = 0; kk < 32; ++kk) {
      float4 av = *(const float4*)&As[kk][ty * 4];
      float4 bv = *(const float4*)&Bs[kk][tx * 4];
      float am[4] = {av.x, av.y, av.z, av.w};
      float bm[4] = {bv.x, bv.y, bv.z, bv.w};
      #pragma unroll
      for (int i = 0; i < 4; ++i)
        #pragma unroll
        for (int j = 0; j < 4; ++j)
          acc[i][j] = fmaf(am[i], bm[j], acc[i][j]);
    }
  }
  #pragma unroll
  for (int i = 0; i < 4; ++i) {
    const int r = row0 + ty * 4 + i;
    #pragma unroll
    for (int j = 0; j < 4; ++j) {
      const int cc = col0 + tx * 4 + j;
      C[(size_t)r * N + cc] = acc[i][j] + b1[cc] + b2[cc];
    }
  }
}

// ---------------- Fused 2-layer persistent recurrent kernel ----------------
__global__ __launch_bounds__(512) void lstm_rec2(
    const float* __restrict__ Whh0,
    const float* __restrict__ Wih1,
    const float* __restrict__ Whh1,
    const float* __restrict__ G,
    const float* __restrict__ bih1, const float* __restrict__ bhh1,
    const float* __restrict__ h0v,
    const float* __restrict__ c0v,
    unsigned* Hrow0, unsigned* Hrow1,    // [T+1][1024] packed f16 pairs
    unsigned* flags0, unsigned* flags1,  // [T+1][256]
    float* __restrict__ hn, float* __restrict__ cn)
{
  const int b = blockIdx.x;
  const int tid = threadIdx.x;
  const int w = tid >> 6;
  const int lane = tid & 63;
  const int j = b * 8 + w;
  __shared__ unsigned hs0[2][HID / 2];
  __shared__ unsigned hs1[2][HID / 2];
  __shared__ float hloc0[8], hloc1[8];

  h2_t wreg0[4][16], wregI[4][16], wregH[4][16];
  #pragma unroll
  for (int g = 0; g < 4; ++g) {
    const float* r0 = Whh0 + (size_t)(g * 2048 + j) * 2048 + 2 * lane;
    #pragma unroll
    for (int it = 0; it < 16; ++it) {
      float2 v = *(const float2*)(r0 + 128 * it);
      wreg0[g][it] = pk2(v.x, v.y);
    }
  }
  #pragma unroll
  for (int g = 0; g < 4; ++g) {
    const float* rI = Wih1 + (size_t)(g * 2048 + j) * 2048 + 2 * lane;
    #pragma unroll
    for (int it = 0; it < 16; ++it) {
      float2 v = *(const float2*)(rI + 128 * it);
      wregI[g][it] = pk2(v.x, v.y);
    }
  }
  #pragma unroll
  for (int g = 0; g < 4; ++g) {
    const float* rH = Whh1 + (size_t)(g * 2048 + j) * 2048 + 2 * lane;
    #pragma unroll
    for (int it = 0; it < 16; ++it) {
      float2 v = *(const float2*)(rH + 128 * it);
      wregH[g][it] = pk2(v.x, v.y);
    }
  }
  float bias1[4];
  #pragma unroll
  for (int g = 0; g < 4; ++g)
    bias1[g] = bih1[g * 2048 + j] + bhh1[g * 2048 + j];

  float c0val = c0v[j];
  float c1val = c0v[HID + j];
  float h0last = 0.f, h1last = 0.f;

  if (tid == 0) {
    u32x4 P = {pku(h0v[b*8+0], h0v[b*8+1]),
               pku(h0v[b*8+2], h0v[b*8+3]),
               pku(h0v[b*8+4], h0v[b*8+5]),
               pku(h0v[b*8+6], h0v[b*8+7])};
    st_sc16(Hrow0 + b * 4, P);
    st_sc4(flags0 + b, 1u);
  }
  if (tid == 64) {
    u32x4 P = {pku(h0v[HID+b*8+0], h0v[HID+b*8+1]),
               pku(h0v[HID+b*8+2], h0v[HID+b*8+3]),
               pku(h0v[HID+b*8+4], h0v[HID+b*8+5]),
               pku(h0v[HID+b*8+6], h0v[HID+b*8+7])};
    st_sc16(Hrow1 + b * 4, P);
    st_sc4(flags1 + b, 1u);
  }

  for (int r = 1; r <= T_LEN + 1; ++r) {
    const bool doL0 = (r <= T_LEN);
    const bool doL1 = (r >= 2);
    float gpre = (doL0 && lane < 4) ? G[(size_t)(r - 1) * G4 + lane * 2048 + j] : 0.f;

    if (w == 0)        poll_flags(flags0 + (size_t)(r - 1) * 256, (unsigned)r, lane);
    else if (w == 1 && doL1) poll_flags(flags1 + (size_t)(r - 2) * 256, (unsigned)(r - 1), lane);
    __syncthreads();

    if (tid < 256) {
      uint4 u = ld_sc16(Hrow0 + (size_t)(r - 1) * 1024 + 4 * tid);
      *(uint4*)&hs0[r & 1][4 * tid] = u;
    } else if (doL1) {
      const int q = tid - 256;
      uint4 u = ld_sc16(Hrow1 + (size_t)(r - 2) * 1024 + 4 * q);
      *(uint4*)&hs1[r & 1][4 * q] = u;
    }
    __syncthreads();

    if (doL0) {
      const unsigned* hr = hs0[r & 1];
      float a0 = 0.f, a1 = 0.f, a2 = 0.f, a3 = 0.f;
      #pragma unroll
      for (int it = 0; it < 16; ++it) {
        h2_t hv = __builtin_bit_cast(h2_t, hr[lane + 64 * it]);
        a0 = __builtin_amdgcn_fdot2(wreg0[0][it], hv, a0, false);
        a1 = __builtin_amdgcn_fdot2(wreg0[1][it], hv, a1, false);
        a2 = __builtin_amdgcn_fdot2(wreg0[2][it], hv, a2, false);
        a3 = __builtin_amdgcn_fdot2(wreg0[3][it], hv, a3, false);
      }
      #pragma unroll
      for (int off = 32; off > 0; off >>= 1) {
        a0 += __shfl_xor(a0, off, 64);
        a1 += __shfl_xor(a1, off, 64);
        a2 += __shfl_xor(a2, off, 64);
        a3 += __shfl_xor(a3, off, 64);
      }
      float g0 = __shfl(gpre, 0, 64), g1 = __shfl(gpre, 1, 64);
      float g2 = __shfl(gpre, 2, 64), g3 = __shfl(gpre, 3, 64);
      float ig = fsigmoid(a0 + g0);
      float fg = fsigmoid(a1 + g1);
      float gg = ftanh(a2 + g2);
      float og = fsigmoid(a3 + g3);
      c0val = fg * c0val + ig * gg;
      h0last = og * ftanh(c0val);
      if (lane == 0) hloc0[w] = h0last;
    }
    __syncthreads();
    if (doL0 && tid == 0) {
      u32x4 P = {pku(hloc0[0], hloc0[1]), pku(hloc0[2], hloc0[3]),
                 pku(hloc0[4], hloc0[5]), pku(hloc0[6], hloc0[7])};
      st_sc16(Hrow0 + (size_t)r * 1024 + b * 4, P);
      st_sc4(flags0 + (size_t)r * 256 + b, (unsigned)(r + 1));
    }

    if (doL1) {
      const unsigned* xr = hs0[r & 1];
      const unsigned* hr = hs1[r & 1];
      float a0 = 0.f, a1 = 0.f, a2 = 0.f, a3 = 0.f;
      #pragma unroll
      for (int it = 0; it < 16; ++it) {
        h2_t xv = __builtin_bit_cast(h2_t, xr[lane + 64 * it]);
        a0 = __builtin_amdgcn_fdot2(wregI[0][it], xv, a0, false);
        a1 = __builtin_amdgcn_fdot2(wregI[1][it], xv, a1, false);
        a2 = __builtin_amdgcn_fdot2(wregI[2][it], xv, a2, false);
        a3 = __builtin_amdgcn_fdot2(wregI[3][it], xv, a3, false);
        h2_t hv = __builtin_bit_cast(h2_t, hr[lane + 64 * it]);
        a0 = __builtin_amdgcn_fdot2(wregH[0][it], hv, a0, false);
        a1 = __builtin_amdgcn_fdot2(wregH[1][it], hv, a1, false);
        a2 = __builtin_amdgcn_fdot2(wregH[2][it], hv, a2, false);
        a3 = __builtin_amdgcn_fdot2(wregH[3][it], hv, a3, false);
      }
      #pragma unroll
      for (int off = 32; off > 0; off >>= 1) {
        a0 += __shfl_xor(a0, off, 64);
        a1 += __shfl_xor(a1, off, 64);
        a2 += __shfl_xor(a2, off, 64);
        a3 += __shfl_xor(a3, off, 64);
      }
      float ig = fsigmoid(a0 + bias1[0]);
      float fg = fsigmoid(a1 + bias1[1]);
      float gg = ftanh(a2 + bias1[2]);
      float og = fsigmoid(a3 + bias1[3]);
      c1val = fg * c1val + ig * gg;
      h1last = og * ftanh(c1val);
      if (lane == 0) hloc1[w] = h1last;
    }
    __syncthreads();
    if (doL1 && tid == 64) {
      u32x4 P = {pku(hloc1[0], hloc1[1]), pku(hloc1[2], hloc1[3]),
                 pku(hloc1[4], hloc1[5]), pku(hloc1[6], hloc1[7])};
      st_sc16(Hrow1 + (size_t)(r - 1) * 1024 + b * 4, P);
      st_sc4(flags1 + (size_t)(r - 1) * 256 + b, (unsigned)r);
    }
  }
  if (lane == 0) {
    hn[j] = h0last;       cn[j] = c0val;
    hn[HID + j] = h1last; cn[HID + j] = c1val;
  }
}

// ---------------- FC + log_softmax ----------------
__global__ __launch_bounds__(128) void fc_lsm(
    const unsigned* __restrict__ Hrows,
    const float* __restrict__ fcw,
    const float* __restrict__ fcb,
    float* __restrict__ out)
{
  const int t = blockIdx.x;
  const int v = threadIdx.x;
  __shared__ float hs[HID];
  __shared__ float red[4];
  const unsigned* hrow = Hrows + (size_t)t * 1024;
  for (int q = v; q < 256; q += 128) {
    uint4 uv = *(const uint4*)&hrow[q * 4];
    hs[q*8+0] = uplo(uv.x); hs[q*8+1] = uphi(uv.x);
    hs[q*8+2] = uplo(uv.y); hs[q*8+3] = uphi(uv.y);
    hs[q*8+4] = uplo(uv.z); hs[q*8+5] = uphi(uv.z);
    hs[q*8+6] = uplo(uv.w); hs[q*8+7] = uphi(uv.w);
  }
  __syncthreads();
  const float* wrow = fcw + (size_t)v * HID;
  float acc = fcb[v];
  #pragma unroll 4
  for (int k = 0; k < HID; k += 4) {
    float4 wv = *(const float4*)&wrow[k];
    acc = fmaf(wv.x, hs[k],     acc);
    acc = fmaf(wv.y, hs[k + 1], acc);
    acc = fmaf(wv.z, hs[k + 2], acc);
    acc = fmaf(wv.w, hs[k + 3], acc);
  }
  float m = acc;
  #pragma unroll
  for (int off = 32; off > 0; off >>= 1) m = fmaxf(m, __shfl_xor(m, off, 64));
  if ((v & 63) == 0) red[v >> 6] = m;
  __syncthreads();
  m = fmaxf(red[0], red[1]);
  float e = expf(acc - m), s = e;
  #pragma unroll
  for (int off = 32; off > 0; off >>= 1) s += __shfl_xor(s, off, 64);
  if ((v & 63) == 0) red[2 + (v >> 6)] = s;
  __syncthreads();
  s = red[2] + red[3];
  out[(size_t)t * NV + v] = (acc - m) - logf(s);
}

extern "C" void kernel_launch(void* const* d_in, const int* in_sizes, int n_in,
                              void* d_out, int out_size, void* d_ws, size_t ws_size,
                              hipStream_t stream) {
  const float* x   = (const float*)d_in[0];
  const float* h0  = (const float*)d_in[1];
  const float* c0  = (const float*)d_in[2];
  const float* Wih = (const float*)d_in[3];
  const float* Whh = (const float*)d_in[4];
  const float* bih = (const float*)d_in[5];
  const float* bhh = (const float*)d_in[6];
  const float* fcw = (const float*)d_in[7];
  const float* fcb = (const float*)d_in[8];
  float* out = (float*)d_out;

  char* ws = (char*)d_ws;
  float*    G      = (float*)(ws);
  unsigned* Hrow0  = (unsigned*)(ws + 67108864);
  unsigned* Hrow1  = (unsigned*)(ws + 67108864 + 8392704);
  unsigned* flags0 = (unsigned*)(ws + 67108864 + 2 * 8392704);
  unsigned* flags1 = (unsigned*)(ws + 67108864 + 2 * 8392704 + 2098176);

  const int nflag4 = (2 * 2098176) / 16;
  zero_flags<<<256, 256, 0, stream>>>(flags0, nflag4);

  dim3 ggrid(G4 / 64, T_LEN / 64);  // (128, 32)

  gemm_bias<<<ggrid, 256, 0, stream>>>(x, Wih, bih, bhh, G);
  lstm_rec2<<<256, 512, 0, stream>>>(Whh, Wih + (size_t)G4 * HID,
                                     Whh + (size_t)G4 * HID, G,
                                     bih + G4, bhh + G4, h0, c0,
                                     Hrow0, Hrow1, flags0, flags1,
                                     out + 262144, out + 266240);
  fc_lsm<<<T_LEN, 128, 0, stream>>>(Hrow1 + 1024, fcw, fcb, out);
}